// Round 3
// baseline (448.782 us; speedup 1.0000x reference)
//
#include <hip/hip_runtime.h>
#include <cstdint>
#include <cstddef>

// ---------------------------------------------------------------------------
// Types / helpers
// ---------------------------------------------------------------------------
typedef short bf16x8 __attribute__((ext_vector_type(8)));
typedef float f32x4 __attribute__((ext_vector_type(4)));

#define D_MODEL 1024
#define SEQ     2048
#define NBATCH  2
#define NH      16
#define DKH     64
#define DFF     4096
#define MROWS   (NBATCH * SEQ)   // 4096

__device__ __forceinline__ unsigned short f2bf(float f) {
  unsigned u = __builtin_bit_cast(unsigned, f);
  u += 0x7fffu + ((u >> 16) & 1u);          // round-to-nearest-even
  return (unsigned short)(u >> 16);
}
__device__ __forceinline__ unsigned packbf2(float lo, float hi) {
  unsigned r;
  asm("v_cvt_pk_bf16_f32 %0, %1, %2" : "=v"(r) : "v"(lo), "v"(hi));
  return r;
}
__device__ __forceinline__ void gload_lds16(const void* g, void* l) {
  __builtin_amdgcn_global_load_lds(
      (const __attribute__((address_space(1))) unsigned*)g,
      (__attribute__((address_space(3))) unsigned*)l, 16, 0, 0);
}

// ---------------------------------------------------------------------------
// Weight cast f32 -> bf16.  dst layout: [wq 1M][wk 1M][wv 1M][wo 1M][w1 4M][w2 4M]
// ---------------------------------------------------------------------------
__global__ __launch_bounds__(256) void cast_weights_kernel(
    const float* __restrict__ wq, const float* __restrict__ wk,
    const float* __restrict__ wv, const float* __restrict__ wo,
    const float* __restrict__ w1, const float* __restrict__ w2,
    unsigned short* __restrict__ dst) {
  const int TOT4 = (12 << 20) >> 2;
  for (int i4 = blockIdx.x * blockDim.x + threadIdx.x; i4 < TOT4;
       i4 += gridDim.x * blockDim.x) {
    int i = i4 << 2;
    const float* src;
    int off;
    if (i < (4 << 20)) {
      src = (i < (2 << 20)) ? ((i < (1 << 20)) ? wq : wk)
                            : ((i < (3 << 20)) ? wv : wo);
      off = i & ((1 << 20) - 1);
    } else if (i < (8 << 20)) { src = w1; off = i - (4 << 20); }
    else                      { src = w2; off = i - (8 << 20); }
    float4 v = *(const float4*)(src + off);
    ushort4 o;
    o.x = f2bf(v.x); o.y = f2bf(v.y); o.z = f2bf(v.z); o.w = f2bf(v.w);
    *(ushort4*)(dst + i) = o;
  }
}

// ---------------------------------------------------------------------------
// LayerNorm (torch semantics: unbiased std, eps added to std) -> bf16
// ---------------------------------------------------------------------------
__global__ __launch_bounds__(256) void ln_kernel(
    const float* __restrict__ x, const float* __restrict__ alpha,
    const float* __restrict__ beta, unsigned short* __restrict__ out) {
  const int row = blockIdx.x;
  const int t = threadIdx.x;
  float4 v = *(const float4*)(x + (size_t)row * D_MODEL + t * 4);
  float s = v.x + v.y + v.z + v.w;
#pragma unroll
  for (int o = 1; o < 64; o <<= 1) s += __shfl_xor(s, o, 64);
  __shared__ float red[8];
  if ((t & 63) == 0) red[t >> 6] = s;
  __syncthreads();
  float mean = (red[0] + red[1] + red[2] + red[3]) * (1.f / D_MODEL);
  float dx = v.x - mean, dy = v.y - mean, dz = v.z - mean, dw = v.w - mean;
  float sq = dx * dx + dy * dy + dz * dz + dw * dw;
#pragma unroll
  for (int o = 1; o < 64; o <<= 1) sq += __shfl_xor(sq, o, 64);
  if ((t & 63) == 0) red[4 + (t >> 6)] = sq;
  __syncthreads();
  float var = (red[4] + red[5] + red[6] + red[7]) * (1.f / (D_MODEL - 1));
  float inv = 1.f / (sqrtf(var) + 1e-6f);
  float4 a = *(const float4*)(alpha + t * 4);
  float4 be = *(const float4*)(beta + t * 4);
  ushort4 o4;
  o4.x = f2bf(a.x * dx * inv + be.x);
  o4.y = f2bf(a.y * dy * inv + be.y);
  o4.z = f2bf(a.z * dz * inv + be.z);
  o4.w = f2bf(a.w * dw * inv + be.w);
  *(ushort4*)(out + (size_t)row * D_MODEL + t * 4) = o4;
}

// ---------------------------------------------------------------------------
// GEMM core macros (128x128 tile, BK=32, 4 waves 2x2, double-buffered LDS)
// C[m][n] = sum_k A[m][k] * W[n][k]   (torch Linear: x @ W^T)
// ---------------------------------------------------------------------------
#define GEMM_STAGE(A_, W_, K_, kt_, buf_)                                          \
  {                                                                                \
    int ke_ = (kt_) * 32;                                                          \
    gload_lds16(A_ + (size_t)(m0 + srow) * (K_) + ke_ + sce, &lds[(buf_)][0][t * 8]);        \
    gload_lds16(A_ + (size_t)(m0 + 64 + srow) * (K_) + ke_ + sce, &lds[(buf_)][0][2048 + t * 8]); \
    gload_lds16(W_ + (size_t)(n0 + srow) * (K_) + ke_ + sce, &lds[(buf_)][1][t * 8]);        \
    gload_lds16(W_ + (size_t)(n0 + 64 + srow) * (K_) + ke_ + sce, &lds[(buf_)][1][2048 + t * 8]); \
  }

#define GEMM_MAINLOOP(A_, W_, K_)                                                  \
  GEMM_STAGE(A_, W_, K_, 0, 0);                                                    \
  for (int kt = 0; kt < ((K_) >> 5); ++kt) {                                       \
    __syncthreads();                                                               \
    if (kt + 1 < ((K_) >> 5)) GEMM_STAGE(A_, W_, K_, kt + 1, (kt + 1) & 1);        \
    const unsigned short* la = lds[kt & 1][0];                                     \
    const unsigned short* lb = lds[kt & 1][1];                                     \
    bf16x8 af[4], bfr[4];                                                          \
    _Pragma("unroll") for (int i = 0; i < 4; i++) {                                \
      af[i]  = *(const bf16x8*)&la[(wm + i * 16 + c) * 32 + g * 8];                \
      bfr[i] = *(const bf16x8*)&lb[(wn + i * 16 + c) * 32 + g * 8];                \
    }                                                                              \
    _Pragma("unroll") for (int mi = 0; mi < 4; mi++)                               \
      _Pragma("unroll") for (int ni = 0; ni < 4; ni++)                             \
        acc[mi][ni] = __builtin_amdgcn_mfma_f32_16x16x32_bf16(af[mi], bfr[ni],     \
                                                              acc[mi][ni], 0, 0, 0); \
  }

enum { MODE_BF16 = 0, MODE_RELU = 2, MODE_RESF32 = 3 };

template <int MODE>
__global__ __launch_bounds__(256) void gemm_bt(
    const unsigned short* __restrict__ A, const unsigned short* __restrict__ W,
    const float* __restrict__ bias, const float* __restrict__ res,
    void* __restrict__ outp, int M, int N, int K) {
  __shared__ unsigned short lds[2][2][128 * 32];
  const int t = threadIdx.x;
  const int lane = t & 63, wid = t >> 6;
  const int g = lane >> 4, c = lane & 15;
  const int m0 = blockIdx.y * 128, n0 = blockIdx.x * 128;
  const int wm = (wid >> 1) * 64, wn = (wid & 1) * 64;
  const int srow = t >> 2, sce = (t & 3) * 8;
  (void)M;

  f32x4 zero = {0.f, 0.f, 0.f, 0.f};
  f32x4 acc[4][4];
#pragma unroll
  for (int i = 0; i < 4; i++)
#pragma unroll
    for (int j = 0; j < 4; j++) acc[i][j] = zero;

  GEMM_MAINLOOP(A, W, K);

  float bv[4];
#pragma unroll
  for (int ni = 0; ni < 4; ni++) bv[ni] = bias[n0 + wn + ni * 16 + c];

#pragma unroll
  for (int mi = 0; mi < 4; mi++) {
#pragma unroll
    for (int ni = 0; ni < 4; ni++) {
      const int mb = m0 + wm + mi * 16 + g * 4;
      const int n = n0 + wn + ni * 16 + c;
#pragma unroll
      for (int r = 0; r < 4; r++) {
        const int m = mb + r;
        float v = acc[mi][ni][r] + bv[ni];
        if (MODE == MODE_RELU) v = fmaxf(v, 0.f);
        if (MODE == MODE_RESF32) {
          ((float*)outp)[(size_t)m * N + n] = v + res[(size_t)m * N + n];
        } else {
          ((unsigned short*)outp)[(size_t)m * N + n] = f2bf(v);
        }
      }
    }
  }
}

// Fused QKV GEMM: grid.x = 24 (3 weights x 8 n-tiles). Q written pre-scaled by
// 1/sqrt(d_k); Q,K (B*S,1024) bf16; V written transposed as Vt (B,H,dk,S) bf16.
__global__ __launch_bounds__(256) void gemm_qkv(
    const unsigned short* __restrict__ A, const unsigned short* __restrict__ Wbase,
    const float* __restrict__ bq, const float* __restrict__ bk,
    const float* __restrict__ bv_, unsigned short* __restrict__ qkout,
    unsigned short* __restrict__ vtout) {
  __shared__ unsigned short lds[2][2][128 * 32];
  const int t = threadIdx.x;
  const int lane = t & 63, wid = t >> 6;
  const int g = lane >> 4, c = lane & 15;
  const int wsel = blockIdx.x >> 3;
  const int m0 = blockIdx.y * 128, n0 = (blockIdx.x & 7) * 128;
  const int wm = (wid >> 1) * 64, wn = (wid & 1) * 64;
  const int srow = t >> 2, sce = (t & 3) * 8;
  const unsigned short* W = Wbase + ((size_t)wsel << 20);
  const float* bias = (wsel == 0) ? bq : (wsel == 1) ? bk : bv_;

  f32x4 zero = {0.f, 0.f, 0.f, 0.f};
  f32x4 acc[4][4];
#pragma unroll
  for (int i = 0; i < 4; i++)
#pragma unroll
    for (int j = 0; j < 4; j++) acc[i][j] = zero;

  GEMM_MAINLOOP(A, W, 1024);

  float bvv[4];
#pragma unroll
  for (int ni = 0; ni < 4; ni++) bvv[ni] = bias[n0 + wn + ni * 16 + c];
  const float qsc = (wsel == 0) ? 0.125f : 1.f;   // fold 1/sqrt(64) into Q

  if (wsel < 2) {
    unsigned short* outp = qkout + ((size_t)wsel << 22);  // q then k
#pragma unroll
    for (int mi = 0; mi < 4; mi++) {
#pragma unroll
      for (int ni = 0; ni < 4; ni++) {
        const int mb = m0 + wm + mi * 16 + g * 4;
        const int n = n0 + wn + ni * 16 + c;
#pragma unroll
        for (int r = 0; r < 4; r++)
          outp[(size_t)(mb + r) * 1024 + n] = f2bf((acc[mi][ni][r] + bvv[ni]) * qsc);
      }
    }
  } else {
    // V^T: out[(b*1024 + n)*2048 + s], n = h*64+dk, m = b*2048+s
#pragma unroll
    for (int mi = 0; mi < 4; mi++) {
#pragma unroll
      for (int ni = 0; ni < 4; ni++) {
        const int mb = m0 + wm + mi * 16 + g * 4;
        const int n = n0 + wn + ni * 16 + c;
        const int b = mb >> 11, s2 = mb & 2047;
        ushort4 o4;
        o4.x = f2bf(acc[mi][ni][0] + bvv[ni]);
        o4.y = f2bf(acc[mi][ni][1] + bvv[ni]);
        o4.z = f2bf(acc[mi][ni][2] + bvv[ni]);
        o4.w = f2bf(acc[mi][ni][3] + bvv[ni]);
        *(ushort4*)(vtout + ((size_t)(b * 1024 + n)) * 2048 + s2) = o4;
      }
    }
  }
}

// ---------------------------------------------------------------------------
// Flash attention, LDS-free (K/V are L2-resident: 512KB per (b,h)).
// grid = (S/64, B*H), 256 thr = 4 waves x 16 q-rows.
// S^T = mfma(K, Q) (softmax row per lane-column; reduce = 2 shfl_xor),
// defer-max online softmax, O^T = mfma(V^T, P).  No barriers at all.
// ---------------------------------------------------------------------------
__global__ __launch_bounds__(256, 4) void attn_kernel(
    const unsigned short* __restrict__ Q, const unsigned short* __restrict__ Kmat,
    const unsigned short* __restrict__ Vt, const int* __restrict__ mask,
    unsigned short* __restrict__ O) {
  const int t = threadIdx.x, lane = t & 63, wid = t >> 6;
  const int g = lane >> 4, c = lane & 15;
  const int qt = blockIdx.x, bh = blockIdx.y;
  const int b = bh >> 4, h = bh & 15;
  const int q0 = qt * 64 + wid * 16;

  const unsigned short* Qb = Q + (size_t)b * SEQ * D_MODEL + h * DKH;
  const unsigned short* Kb = Kmat + (size_t)b * SEQ * D_MODEL + h * DKH;
  const unsigned short* Vb = Vt + (size_t)bh * DKH * SEQ;
  const int* mb = mask + b * SEQ;

  bf16x8 qf[2];
#pragma unroll
  for (int kd = 0; kd < 2; kd++)
    qf[kd] = *(const bf16x8*)&Qb[(size_t)(q0 + c) * D_MODEL + kd * 32 + g * 8];

  f32x4 zero = {0.f, 0.f, 0.f, 0.f};
  f32x4 of[4];
#pragma unroll
  for (int j = 0; j < 4; j++) of[j] = zero;
  float mrun = -1e30f, lrun = 0.f;

  bf16x8 kf[4];  // [nb][kd]
#pragma unroll
  for (int nb = 0; nb < 2; nb++)
#pragma unroll
    for (int kd = 0; kd < 2; kd++)
      kf[nb * 2 + kd] =
          *(const bf16x8*)&Kb[(size_t)(nb * 16 + c) * D_MODEL + kd * 32 + g * 8];

  for (int kv = 0; kv < 64; ++kv) {
    const int base = kv * 32;

    // V fragments for this tile (consumed at PV, after softmax)
    bf16x8 vf[4];
#pragma unroll
    for (int dkb = 0; dkb < 4; dkb++)
      vf[dkb] = *(const bf16x8*)&Vb[(size_t)(dkb * 16 + c) * SEQ + base + g * 8];

    int4 mk0 = *(const int4*)&mb[base + g * 4];
    int4 mk1 = *(const int4*)&mb[base + 16 + g * 4];

    // S^T[kv][q] (Q pre-scaled by 1/8)
    f32x4 sf[2];
#pragma unroll
    for (int nb = 0; nb < 2; nb++) {
      f32x4 s = zero;
      s = __builtin_amdgcn_mfma_f32_16x16x32_bf16(kf[nb * 2 + 0], qf[0], s, 0, 0, 0);
      s = __builtin_amdgcn_mfma_f32_16x16x32_bf16(kf[nb * 2 + 1], qf[1], s, 0, 0, 0);
      sf[nb] = s;
    }

    // prefetch next K tile under softmax
    bf16x8 kfn[4];
    if (kv < 63) {
#pragma unroll
      for (int nb = 0; nb < 2; nb++)
#pragma unroll
        for (int kd = 0; kd < 2; kd++)
          kfn[nb * 2 + kd] = *(const bf16x8*)&Kb[(size_t)(base + 32 + nb * 16 + c) *
                                                     D_MODEL + kd * 32 + g * 8];
    }

    // additive mask
    sf[0][0] += (mk0.x == 0) ? -1e9f : 0.f;
    sf[0][1] += (mk0.y == 0) ? -1e9f : 0.f;
    sf[0][2] += (mk0.z == 0) ? -1e9f : 0.f;
    sf[0][3] += (mk0.w == 0) ? -1e9f : 0.f;
    sf[1][0] += (mk1.x == 0) ? -1e9f : 0.f;
    sf[1][1] += (mk1.y == 0) ? -1e9f : 0.f;
    sf[1][2] += (mk1.z == 0) ? -1e9f : 0.f;
    sf[1][3] += (mk1.w == 0) ? -1e9f : 0.f;

    // online softmax with defer-max (THR=8)
    float pm = fmaxf(fmaxf(fmaxf(sf[0][0], sf[0][1]), fmaxf(sf[0][2], sf[0][3])),
                     fmaxf(fmaxf(sf[1][0], sf[1][1]), fmaxf(sf[1][2], sf[1][3])));
    pm = fmaxf(pm, __shfl_xor(pm, 16, 64));
    pm = fmaxf(pm, __shfl_xor(pm, 32, 64));
    if (!__all(pm <= mrun + 8.f)) {
      float mnew = fmaxf(mrun, pm);
      float fsc = exp2f((mrun - mnew) * 1.44269504f);
      lrun *= fsc;
#pragma unroll
      for (int dkb = 0; dkb < 4; dkb++) of[dkb] *= fsc;
      mrun = mnew;
    }
    const float mb2 = mrun * 1.44269504f;
    float ps = 0.f;
#pragma unroll
    for (int nb = 0; nb < 2; nb++)
#pragma unroll
      for (int r = 0; r < 4; r++) {
        float p = exp2f(fmaf(sf[nb][r], 1.44269504f, -mb2));
        sf[nb][r] = p;
        ps += p;
      }
    lrun += ps;

    // P^T (row=kv,col=q) -> PV B-fragment: dest lane (g,c), pos j needs kv=8g+j
    unsigned pk00 = packbf2(sf[0][0], sf[0][1]);
    unsigned pk01 = packbf2(sf[0][2], sf[0][3]);
    unsigned pk10 = packbf2(sf[1][0], sf[1][1]);
    unsigned pk11 = packbf2(sf[1][2], sf[1][3]);
    const int la = ((g & 1) << 5) + c;
    const int lb2 = la + 16;
    unsigned a00 = __shfl(pk00, la, 64), a01 = __shfl(pk01, la, 64);
    unsigned a10 = __shfl(pk10, la, 64), a11 = __shfl(pk11, la, 64);
    unsigned b00 = __shfl(pk00, lb2, 64), b01 = __shfl(pk01, lb2, 64);
    unsigned b10 = __shfl(pk10, lb2, 64), b11 = __shfl(pk11, lb2, 64);
    const bool hi2 = (g >= 2);
    uint4 pw;
    pw.x = hi2 ? a10 : a00;
    pw.y = hi2 ? a11 : a01;
    pw.z = hi2 ? b10 : b00;
    pw.w = hi2 ? b11 : b01;
    bf16x8 pf = __builtin_bit_cast(bf16x8, pw);
#pragma unroll
    for (int dkb = 0; dkb < 4; dkb++)
      of[dkb] = __builtin_amdgcn_mfma_f32_16x16x32_bf16(vf[dkb], pf, of[dkb], 0, 0, 0);

#pragma unroll
    for (int i = 0; i < 4; i++) kf[i] = kfn[i];
  }

  float lt = lrun;
  lt += __shfl_xor(lt, 16, 64);
  lt += __shfl_xor(lt, 32, 64);
  float inv = 1.f / lt;
#pragma unroll
  for (int dkb = 0; dkb < 4; dkb++) {
    ushort4 o4;
    o4.x = f2bf(of[dkb][0] * inv);
    o4.y = f2bf(of[dkb][1] * inv);
    o4.z = f2bf(of[dkb][2] * inv);
    o4.w = f2bf(of[dkb][3] * inv);
    *(ushort4*)&O[(size_t)(b * SEQ + q0 + c) * D_MODEL + h * DKH + dkb * 16 +
                  g * 4] = o4;
  }
}

// ---------------------------------------------------------------------------
// Launch
// ---------------------------------------------------------------------------
extern "C" void kernel_launch(void* const* d_in, const int* in_sizes, int n_in,
                              void* d_out, int out_size, void* d_ws, size_t ws_size,
                              hipStream_t stream) {
  (void)in_sizes; (void)n_in; (void)out_size; (void)ws_size;
  const float* x    = (const float*)d_in[0];
  const int*   mask = (const int*)d_in[1];
  const float* wq   = (const float*)d_in[2];
  const float* bq   = (const float*)d_in[3];
  const float* wk   = (const float*)d_in[4];
  const float* bk   = (const float*)d_in[5];
  const float* wv   = (const float*)d_in[6];
  const float* bv   = (const float*)d_in[7];
  const float* wo   = (const float*)d_in[8];
  const float* bo   = (const float*)d_in[9];
  const float* w1   = (const float*)d_in[10];
  const float* b1   = (const float*)d_in[11];
  const float* w2   = (const float*)d_in[12];
  const float* b2   = (const float*)d_in[13];
  const float* ln1a = (const float*)d_in[14];
  const float* ln1b = (const float*)d_in[15];
  const float* ln2a = (const float*)d_in[16];
  const float* ln2b = (const float*)d_in[17];

  char* ws = (char*)d_ws;
  unsigned short* w_bf  = (unsigned short*)ws;            // 24 MB total bf16 weights
  unsigned short* wq_bf = w_bf;
  unsigned short* wo_bf = w_bf + (3u << 20);
  unsigned short* w1_bf = w_bf + (4u << 20);
  unsigned short* w2_bf = w_bf + (8u << 20);
  unsigned short* h1    = (unsigned short*)(ws + (24u << 20));
  unsigned short* qbuf  = (unsigned short*)(ws + (32u << 20));  // k at +8MB
  unsigned short* vtbuf = (unsigned short*)(ws + (48u << 20));
  unsigned short* attnb = (unsigned short*)(ws + (56u << 20));
  float*          x2    = (float*)(ws + (64u << 20));
  unsigned short* h2    = (unsigned short*)(ws + (80u << 20));
  unsigned short* ffn1  = (unsigned short*)(ws + (88u << 20));  // 32 MB -> ends 120MB
  unsigned short* kbuf  = qbuf + (1u << 22);

  cast_weights_kernel<<<1024, 256, 0, stream>>>(wq, wk, wv, wo, w1, w2, w_bf);
  ln_kernel<<<MROWS, 256, 0, stream>>>(x, ln1a, ln1b, h1);
  gemm_qkv<<<dim3(24, 32), 256, 0, stream>>>(h1, wq_bf, bq, bk, bv, qbuf, vtbuf);
  attn_kernel<<<dim3(32, 32), 256, 0, stream>>>(qbuf, kbuf, vtbuf, mask, attnb);
  gemm_bt<MODE_RESF32><<<dim3(8, 32), 256, 0, stream>>>(
      attnb, wo_bf, bo, x, (void*)x2, MROWS, D_MODEL, D_MODEL);
  ln_kernel<<<MROWS, 256, 0, stream>>>(x2, ln2a, ln2b, h2);
  gemm_bt<MODE_RELU><<<dim3(32, 32), 256, 0, stream>>>(
      h2, w1_bf, b1, nullptr, (void*)ffn1, MROWS, DFF, D_MODEL);
  gemm_bt<MODE_RESF32><<<dim3(8, 32), 256, 0, stream>>>(
      ffn1, w2_bf, b2, x2, d_out, MROWS, D_MODEL, DFF);
}

// Round 4
// 297.288 us; speedup vs baseline: 1.5096x; 1.5096x over previous
//
#include <hip/hip_runtime.h>
#include <cstdint>
#include <cstddef>

// ---------------------------------------------------------------------------
// Types / helpers
// ---------------------------------------------------------------------------
typedef short bf16x8 __attribute__((ext_vector_type(8)));
typedef float f32x4 __attribute__((ext_vector_type(4)));

#define D_MODEL 1024
#define SEQ     2048
#define NBATCH  2
#define NH      16
#define DKH     64
#define DFF     4096
#define MROWS   (NBATCH * SEQ)   // 4096

__device__ __forceinline__ unsigned short f2bf(float f) {
  unsigned u = __builtin_bit_cast(unsigned, f);
  u += 0x7fffu + ((u >> 16) & 1u);          // round-to-nearest-even
  return (unsigned short)(u >> 16);
}
__device__ __forceinline__ unsigned packbf2(float lo, float hi) {
  unsigned r;
  asm("v_cvt_pk_bf16_f32 %0, %1, %2" : "=v"(r) : "v"(lo), "v"(hi));
  return r;
}
__device__ __forceinline__ void gload_lds16(const void* g, void* l) {
  __builtin_amdgcn_global_load_lds(
      (const __attribute__((address_space(1))) unsigned*)g,
      (__attribute__((address_space(3))) unsigned*)l, 16, 0, 0);
}

// ---------------------------------------------------------------------------
// Weight cast f32 -> bf16.  dst layout: [wq 1M][wk 1M][wv 1M][wo 1M][w1 4M][w2 4M]
// ---------------------------------------------------------------------------
__global__ __launch_bounds__(256) void cast_weights_kernel(
    const float* __restrict__ wq, const float* __restrict__ wk,
    const float* __restrict__ wv, const float* __restrict__ wo,
    const float* __restrict__ w1, const float* __restrict__ w2,
    unsigned short* __restrict__ dst) {
  const int TOT4 = (12 << 20) >> 2;
  for (int i4 = blockIdx.x * blockDim.x + threadIdx.x; i4 < TOT4;
       i4 += gridDim.x * blockDim.x) {
    int i = i4 << 2;
    const float* src;
    int off;
    if (i < (4 << 20)) {
      src = (i < (2 << 20)) ? ((i < (1 << 20)) ? wq : wk)
                            : ((i < (3 << 20)) ? wv : wo);
      off = i & ((1 << 20) - 1);
    } else if (i < (8 << 20)) { src = w1; off = i - (4 << 20); }
    else                      { src = w2; off = i - (8 << 20); }
    float4 v = *(const float4*)(src + off);
    ushort4 o;
    o.x = f2bf(v.x); o.y = f2bf(v.y); o.z = f2bf(v.z); o.w = f2bf(v.w);
    *(ushort4*)(dst + i) = o;
  }
}

// ---------------------------------------------------------------------------
// LayerNorm (torch semantics: unbiased std, eps added to std) -> bf16
// ---------------------------------------------------------------------------
__global__ __launch_bounds__(256) void ln_kernel(
    const float* __restrict__ x, const float* __restrict__ alpha,
    const float* __restrict__ beta, unsigned short* __restrict__ out) {
  const int row = blockIdx.x;
  const int t = threadIdx.x;
  float4 v = *(const float4*)(x + (size_t)row * D_MODEL + t * 4);
  float s = v.x + v.y + v.z + v.w;
#pragma unroll
  for (int o = 1; o < 64; o <<= 1) s += __shfl_xor(s, o, 64);
  __shared__ float red[8];
  if ((t & 63) == 0) red[t >> 6] = s;
  __syncthreads();
  float mean = (red[0] + red[1] + red[2] + red[3]) * (1.f / D_MODEL);
  float dx = v.x - mean, dy = v.y - mean, dz = v.z - mean, dw = v.w - mean;
  float sq = dx * dx + dy * dy + dz * dz + dw * dw;
#pragma unroll
  for (int o = 1; o < 64; o <<= 1) sq += __shfl_xor(sq, o, 64);
  if ((t & 63) == 0) red[4 + (t >> 6)] = sq;
  __syncthreads();
  float var = (red[4] + red[5] + red[6] + red[7]) * (1.f / (D_MODEL - 1));
  float inv = 1.f / (sqrtf(var) + 1e-6f);
  float4 a = *(const float4*)(alpha + t * 4);
  float4 be = *(const float4*)(beta + t * 4);
  ushort4 o4;
  o4.x = f2bf(a.x * dx * inv + be.x);
  o4.y = f2bf(a.y * dy * inv + be.y);
  o4.z = f2bf(a.z * dz * inv + be.z);
  o4.w = f2bf(a.w * dw * inv + be.w);
  *(ushort4*)(out + (size_t)row * D_MODEL + t * 4) = o4;
}

// ---------------------------------------------------------------------------
// GEMM core macros (128x128 tile, BK=32, 4 waves 2x2, double-buffered LDS)
// C[m][n] = sum_k A[m][k] * W[n][k]   (torch Linear: x @ W^T)
// LD_ = row stride of A/W; koff_ = starting k (split-K support)
// ---------------------------------------------------------------------------
#define GEMM_STAGE(A_, W_, LD_, koff_, kt_, buf_)                                  \
  {                                                                                \
    int ke_ = (koff_) + (kt_) * 32;                                                \
    gload_lds16(A_ + (size_t)(m0 + srow) * (LD_) + ke_ + sce, &lds[(buf_)][0][t * 8]);        \
    gload_lds16(A_ + (size_t)(m0 + 64 + srow) * (LD_) + ke_ + sce, &lds[(buf_)][0][2048 + t * 8]); \
    gload_lds16(W_ + (size_t)(n0 + srow) * (LD_) + ke_ + sce, &lds[(buf_)][1][t * 8]);        \
    gload_lds16(W_ + (size_t)(n0 + 64 + srow) * (LD_) + ke_ + sce, &lds[(buf_)][1][2048 + t * 8]); \
  }

#define GEMM_MAINLOOP(A_, W_, LD_, K_, koff_)                                      \
  GEMM_STAGE(A_, W_, LD_, koff_, 0, 0);                                            \
  for (int kt = 0; kt < ((K_) >> 5); ++kt) {                                       \
    __syncthreads();                                                               \
    if (kt + 1 < ((K_) >> 5)) GEMM_STAGE(A_, W_, LD_, koff_, kt + 1, (kt + 1) & 1); \
    const unsigned short* la = lds[kt & 1][0];                                     \
    const unsigned short* lb = lds[kt & 1][1];                                     \
    bf16x8 af[4], bfr[4];                                                          \
    _Pragma("unroll") for (int i = 0; i < 4; i++) {                                \
      af[i]  = *(const bf16x8*)&la[(wm + i * 16 + c) * 32 + g * 8];                \
      bfr[i] = *(const bf16x8*)&lb[(wn + i * 16 + c) * 32 + g * 8];                \
    }                                                                              \
    _Pragma("unroll") for (int mi = 0; mi < 4; mi++)                               \
      _Pragma("unroll") for (int ni = 0; ni < 4; ni++)                             \
        acc[mi][ni] = __builtin_amdgcn_mfma_f32_16x16x32_bf16(af[mi], bfr[ni],     \
                                                              acc[mi][ni], 0, 0, 0); \
  }

enum { MODE_BF16 = 0, MODE_RELU = 2, MODE_PARTIAL = 4 };

template <int MODE>
__global__ __launch_bounds__(256) void gemm_bt(
    const unsigned short* __restrict__ A, const unsigned short* __restrict__ W,
    const float* __restrict__ bias, void* __restrict__ outp, int M, int N, int K) {
  __shared__ unsigned short lds[2][2][128 * 32];
  const int t = threadIdx.x;
  const int lane = t & 63, wid = t >> 6;
  const int g = lane >> 4, c = lane & 15;
  const int m0 = blockIdx.y * 128, n0 = blockIdx.x * 128;
  const int wm = (wid >> 1) * 64, wn = (wid & 1) * 64;
  const int srow = t >> 2, sce = (t & 3) * 8;
  const int ldk = K * gridDim.z;
  const int koff = blockIdx.z * K;

  f32x4 zero = {0.f, 0.f, 0.f, 0.f};
  f32x4 acc[4][4];
#pragma unroll
  for (int i = 0; i < 4; i++)
#pragma unroll
    for (int j = 0; j < 4; j++) acc[i][j] = zero;

  GEMM_MAINLOOP(A, W, ldk, K, koff);

  float bv[4];
#pragma unroll
  for (int ni = 0; ni < 4; ni++)
    bv[ni] = (MODE == MODE_PARTIAL) ? 0.f : bias[n0 + wn + ni * 16 + c];

  float* po = (MODE == MODE_PARTIAL)
                  ? ((float*)outp + (size_t)blockIdx.z * M * N) : (float*)outp;

#pragma unroll
  for (int mi = 0; mi < 4; mi++) {
#pragma unroll
    for (int ni = 0; ni < 4; ni++) {
      const int mb = m0 + wm + mi * 16 + g * 4;
      const int n = n0 + wn + ni * 16 + c;
#pragma unroll
      for (int r = 0; r < 4; r++) {
        const int m = mb + r;
        float v = acc[mi][ni][r] + bv[ni];
        if (MODE == MODE_RELU) v = fmaxf(v, 0.f);
        if (MODE == MODE_PARTIAL) {
          po[(size_t)m * N + n] = v;
        } else {
          ((unsigned short*)outp)[(size_t)m * N + n] = f2bf(v);
        }
      }
    }
  }
}

// Fused QKV GEMM: grid.x = 24 (3 weights x 8 n-tiles). Q written pre-scaled by
// 1/sqrt(d_k); Q,K (B*S,1024) bf16; V written transposed as Vt (B,H,dk,S) bf16.
__global__ __launch_bounds__(256) void gemm_qkv(
    const unsigned short* __restrict__ A, const unsigned short* __restrict__ Wbase,
    const float* __restrict__ bq, const float* __restrict__ bk,
    const float* __restrict__ bv_, unsigned short* __restrict__ qkout,
    unsigned short* __restrict__ vtout) {
  __shared__ unsigned short lds[2][2][128 * 32];
  const int t = threadIdx.x;
  const int lane = t & 63, wid = t >> 6;
  const int g = lane >> 4, c = lane & 15;
  const int wsel = blockIdx.x >> 3;
  const int m0 = blockIdx.y * 128, n0 = (blockIdx.x & 7) * 128;
  const int wm = (wid >> 1) * 64, wn = (wid & 1) * 64;
  const int srow = t >> 2, sce = (t & 3) * 8;
  const unsigned short* W = Wbase + ((size_t)wsel << 20);
  const float* bias = (wsel == 0) ? bq : (wsel == 1) ? bk : bv_;

  f32x4 zero = {0.f, 0.f, 0.f, 0.f};
  f32x4 acc[4][4];
#pragma unroll
  for (int i = 0; i < 4; i++)
#pragma unroll
    for (int j = 0; j < 4; j++) acc[i][j] = zero;

  GEMM_MAINLOOP(A, W, 1024, 1024, 0);

  float bvv[4];
#pragma unroll
  for (int ni = 0; ni < 4; ni++) bvv[ni] = bias[n0 + wn + ni * 16 + c];
  const float qsc = (wsel == 0) ? 0.125f : 1.f;   // fold 1/sqrt(64) into Q

  if (wsel < 2) {
    unsigned short* outp = qkout + ((size_t)wsel << 22);  // q then k
#pragma unroll
    for (int mi = 0; mi < 4; mi++) {
#pragma unroll
      for (int ni = 0; ni < 4; ni++) {
        const int mb = m0 + wm + mi * 16 + g * 4;
        const int n = n0 + wn + ni * 16 + c;
#pragma unroll
        for (int r = 0; r < 4; r++)
          outp[(size_t)(mb + r) * 1024 + n] = f2bf((acc[mi][ni][r] + bvv[ni]) * qsc);
      }
    }
  } else {
    // V^T: out[(b*1024 + n)*2048 + s], n = h*64+dk, m = b*2048+s
#pragma unroll
    for (int mi = 0; mi < 4; mi++) {
#pragma unroll
      for (int ni = 0; ni < 4; ni++) {
        const int mb = m0 + wm + mi * 16 + g * 4;
        const int n = n0 + wn + ni * 16 + c;
        const int b = mb >> 11, s2 = mb & 2047;
        ushort4 o4;
        o4.x = f2bf(acc[mi][ni][0] + bvv[ni]);
        o4.y = f2bf(acc[mi][ni][1] + bvv[ni]);
        o4.z = f2bf(acc[mi][ni][2] + bvv[ni]);
        o4.w = f2bf(acc[mi][ni][3] + bvv[ni]);
        *(ushort4*)(vtout + ((size_t)(b * 1024 + n)) * 2048 + s2) = o4;
      }
    }
  }
}

// ---------------------------------------------------------------------------
// Flash attention. grid = (S/64, B*H), 256 thr = 4 waves x 16 q-rows.
// K and V^T tiles staged in LDS via global_load_lds with XOR chunk-swizzle on
// the GLOBAL source (rule #21: linear LDS dest, inverse-swz source, swz read).
// S^T = mfma(K, Q), defer-max online softmax, O^T = mfma(V^T, P).
// One barrier per KV-tile, double-buffered.
// ---------------------------------------------------------------------------
#define ATTN_STAGE(base_, buf_)                                                    \
  {                                                                                \
    gload_lds16(Kb + (size_t)((base_) + kr) * D_MODEL + ((kc ^ (kr & 7)) << 3),    \
                &Klds[buf_][t * 8]);                                               \
    gload_lds16(Vb + (size_t)vr * SEQ + (base_) + ((vc2 ^ (vr & 3)) << 3),         \
                &Vlds[buf_][t * 8]);                                               \
  }

__global__ __launch_bounds__(256, 4) void attn_kernel(
    const unsigned short* __restrict__ Q, const unsigned short* __restrict__ Kmat,
    const unsigned short* __restrict__ Vt, const int* __restrict__ mask,
    unsigned short* __restrict__ O) {
  __shared__ unsigned short Klds[2][32 * 64];
  __shared__ unsigned short Vlds[2][64 * 32];
  const int t = threadIdx.x, lane = t & 63, wid = t >> 6;
  const int g = lane >> 4, c = lane & 15;
  const int qt = blockIdx.x, bh = blockIdx.y;
  const int b = bh >> 4, h = bh & 15;
  const int q0 = qt * 64 + wid * 16;

  const unsigned short* Qb = Q + (size_t)b * SEQ * D_MODEL + h * DKH;
  const unsigned short* Kb = Kmat + (size_t)b * SEQ * D_MODEL + h * DKH;
  const unsigned short* Vb = Vt + (size_t)bh * DKH * SEQ;
  const int* mb = mask + b * SEQ;

  // staging indices: K tile 32 rows x 8 chunks(16B); V tile 64 rows x 4 chunks
  const int kr = t >> 3, kc = t & 7;
  const int vr = t >> 2, vc2 = t & 3;

  bf16x8 qf[2];
#pragma unroll
  for (int kd = 0; kd < 2; kd++)
    qf[kd] = *(const bf16x8*)&Qb[(size_t)(q0 + c) * D_MODEL + kd * 32 + g * 8];

  f32x4 zero = {0.f, 0.f, 0.f, 0.f};
  f32x4 of[4];
#pragma unroll
  for (int j = 0; j < 4; j++) of[j] = zero;
  float mrun = -1e30f, lrun = 0.f;

  ATTN_STAGE(0, 0);

  for (int kv = 0; kv < 64; ++kv) {
    const int buf = kv & 1;
    const int base = kv * 32;
    __syncthreads();                       // drains gloads of this buf
    if (kv < 63) ATTN_STAGE(base + 32, buf ^ 1);

    // K fragments: row nb*16+c, global chunk kd*4+g -> LDS chunk ^ (c&7)
    bf16x8 kf[4];
#pragma unroll
    for (int nb = 0; nb < 2; nb++)
#pragma unroll
      for (int kd = 0; kd < 2; kd++)
        kf[nb * 2 + kd] = *(const bf16x8*)&Klds[buf][(nb * 16 + c) * 64 +
                                                     (((kd * 4 + g) ^ (c & 7)) << 3)];
    // V fragments: row dkb*16+c, global chunk g -> LDS chunk g ^ (c&3)
    bf16x8 vf[4];
#pragma unroll
    for (int dkb = 0; dkb < 4; dkb++)
      vf[dkb] = *(const bf16x8*)&Vlds[buf][(dkb * 16 + c) * 32 +
                                           ((g ^ (c & 3)) << 3)];

    int4 mk0 = *(const int4*)&mb[base + g * 4];
    int4 mk1 = *(const int4*)&mb[base + 16 + g * 4];

    // S^T[kv][q] (Q pre-scaled by 1/8)
    f32x4 sf[2];
#pragma unroll
    for (int nb = 0; nb < 2; nb++) {
      f32x4 s = zero;
      s = __builtin_amdgcn_mfma_f32_16x16x32_bf16(kf[nb * 2 + 0], qf[0], s, 0, 0, 0);
      s = __builtin_amdgcn_mfma_f32_16x16x32_bf16(kf[nb * 2 + 1], qf[1], s, 0, 0, 0);
      sf[nb] = s;
    }

    // additive mask
    sf[0][0] += (mk0.x == 0) ? -1e9f : 0.f;
    sf[0][1] += (mk0.y == 0) ? -1e9f : 0.f;
    sf[0][2] += (mk0.z == 0) ? -1e9f : 0.f;
    sf[0][3] += (mk0.w == 0) ? -1e9f : 0.f;
    sf[1][0] += (mk1.x == 0) ? -1e9f : 0.f;
    sf[1][1] += (mk1.y == 0) ? -1e9f : 0.f;
    sf[1][2] += (mk1.z == 0) ? -1e9f : 0.f;
    sf[1][3] += (mk1.w == 0) ? -1e9f : 0.f;

    // online softmax with defer-max (THR=8)
    float pm = fmaxf(fmaxf(fmaxf(sf[0][0], sf[0][1]), fmaxf(sf[0][2], sf[0][3])),
                     fmaxf(fmaxf(sf[1][0], sf[1][1]), fmaxf(sf[1][2], sf[1][3])));
    pm = fmaxf(pm, __shfl_xor(pm, 16, 64));
    pm = fmaxf(pm, __shfl_xor(pm, 32, 64));
    if (!__all(pm <= mrun + 8.f)) {
      float mnew = fmaxf(mrun, pm);
      float fsc = exp2f((mrun - mnew) * 1.44269504f);
      lrun *= fsc;
#pragma unroll
      for (int dkb = 0; dkb < 4; dkb++) of[dkb] *= fsc;
      mrun = mnew;
    }
    const float mb2 = mrun * 1.44269504f;
    float ps = 0.f;
#pragma unroll
    for (int nb = 0; nb < 2; nb++)
#pragma unroll
      for (int r = 0; r < 4; r++) {
        float p = exp2f(fmaf(sf[nb][r], 1.44269504f, -mb2));
        sf[nb][r] = p;
        ps += p;
      }
    lrun += ps;

    // P^T (row=kv,col=q) -> PV B-fragment: dest lane (g,c), pos j needs kv=8g+j
    unsigned pk00 = packbf2(sf[0][0], sf[0][1]);
    unsigned pk01 = packbf2(sf[0][2], sf[0][3]);
    unsigned pk10 = packbf2(sf[1][0], sf[1][1]);
    unsigned pk11 = packbf2(sf[1][2], sf[1][3]);
    const int la = ((g & 1) << 5) + c;
    const int lb2 = la + 16;
    unsigned a00 = __shfl(pk00, la, 64), a01 = __shfl(pk01, la, 64);
    unsigned a10 = __shfl(pk10, la, 64), a11 = __shfl(pk11, la, 64);
    unsigned b00 = __shfl(pk00, lb2, 64), b01 = __shfl(pk01, lb2, 64);
    unsigned b10 = __shfl(pk10, lb2, 64), b11 = __shfl(pk11, lb2, 64);
    const bool hi2 = (g >= 2);
    uint4 pw;
    pw.x = hi2 ? a10 : a00;
    pw.y = hi2 ? a11 : a01;
    pw.z = hi2 ? b10 : b00;
    pw.w = hi2 ? b11 : b01;
    bf16x8 pf = __builtin_bit_cast(bf16x8, pw);
#pragma unroll
    for (int dkb = 0; dkb < 4; dkb++)
      of[dkb] = __builtin_amdgcn_mfma_f32_16x16x32_bf16(vf[dkb], pf, of[dkb], 0, 0, 0);
  }

  float lt = lrun;
  lt += __shfl_xor(lt, 16, 64);
  lt += __shfl_xor(lt, 32, 64);
  float inv = 1.f / lt;
#pragma unroll
  for (int dkb = 0; dkb < 4; dkb++) {
    ushort4 o4;
    o4.x = f2bf(of[dkb][0] * inv);
    o4.y = f2bf(of[dkb][1] * inv);
    o4.z = f2bf(of[dkb][2] * inv);
    o4.w = f2bf(of[dkb][3] * inv);
    *(ushort4*)&O[(size_t)(b * SEQ + q0 + c) * D_MODEL + h * DKH + dkb * 16 +
                  g * 4] = o4;
  }
}

// ---------------------------------------------------------------------------
// Fused epilogues
// proj_ln2: x2 = x + P0 + P1 + bo;  h2 = LN2(x2).  one block per row.
// ---------------------------------------------------------------------------
__global__ __launch_bounds__(256) void proj_ln2_kernel(
    const float* __restrict__ x, const float* __restrict__ P0,
    const float* __restrict__ P1, const float* __restrict__ bo,
    const float* __restrict__ alpha, const float* __restrict__ beta,
    float* __restrict__ x2, unsigned short* __restrict__ h2) {
  const int row = blockIdx.x;
  const int t = threadIdx.x;
  const size_t idx = (size_t)row * D_MODEL + t * 4;
  float4 xv = *(const float4*)(x + idx);
  float4 p0 = *(const float4*)(P0 + idx);
  float4 p1 = *(const float4*)(P1 + idx);
  float4 bo4 = *(const float4*)(bo + t * 4);
  float4 v;
  v.x = xv.x + p0.x + p1.x + bo4.x;
  v.y = xv.y + p0.y + p1.y + bo4.y;
  v.z = xv.z + p0.z + p1.z + bo4.z;
  v.w = xv.w + p0.w + p1.w + bo4.w;
  *(float4*)(x2 + idx) = v;

  float s = v.x + v.y + v.z + v.w;
#pragma unroll
  for (int o = 1; o < 64; o <<= 1) s += __shfl_xor(s, o, 64);
  __shared__ float red[8];
  if ((t & 63) == 0) red[t >> 6] = s;
  __syncthreads();
  float mean = (red[0] + red[1] + red[2] + red[3]) * (1.f / D_MODEL);
  float dx = v.x - mean, dy = v.y - mean, dz = v.z - mean, dw = v.w - mean;
  float sq = dx * dx + dy * dy + dz * dz + dw * dw;
#pragma unroll
  for (int o = 1; o < 64; o <<= 1) sq += __shfl_xor(sq, o, 64);
  if ((t & 63) == 0) red[4 + (t >> 6)] = sq;
  __syncthreads();
  float var = (red[4] + red[5] + red[6] + red[7]) * (1.f / (D_MODEL - 1));
  float inv = 1.f / (sqrtf(var) + 1e-6f);
  float4 a = *(const float4*)(alpha + t * 4);
  float4 be = *(const float4*)(beta + t * 4);
  ushort4 o4;
  o4.x = f2bf(a.x * dx * inv + be.x);
  o4.y = f2bf(a.y * dy * inv + be.y);
  o4.z = f2bf(a.z * dz * inv + be.z);
  o4.w = f2bf(a.w * dw * inv + be.w);
  *(ushort4*)(h2 + idx) = o4;
}

// ffn2_add: out = x2 + Q0 + Q1 + b2  (final output, f32)
__global__ __launch_bounds__(256) void ffn2_add_kernel(
    const float* __restrict__ x2, const float* __restrict__ Q0,
    const float* __restrict__ Q1, const float* __restrict__ b2,
    float* __restrict__ out) {
  const int i4 = blockIdx.x * blockDim.x + threadIdx.x;  // 1M float4s
  const size_t idx = (size_t)i4 * 4;
  float4 a = *(const float4*)(x2 + idx);
  float4 q0 = *(const float4*)(Q0 + idx);
  float4 q1 = *(const float4*)(Q1 + idx);
  float4 b = *(const float4*)(b2 + ((i4 & 255) * 4));
  float4 v;
  v.x = a.x + q0.x + q1.x + b.x;
  v.y = a.y + q0.y + q1.y + b.y;
  v.z = a.z + q0.z + q1.z + b.z;
  v.w = a.w + q0.w + q1.w + b.w;
  *(float4*)(out + idx) = v;
}

// ---------------------------------------------------------------------------
// Launch
// ---------------------------------------------------------------------------
extern "C" void kernel_launch(void* const* d_in, const int* in_sizes, int n_in,
                              void* d_out, int out_size, void* d_ws, size_t ws_size,
                              hipStream_t stream) {
  (void)in_sizes; (void)n_in; (void)out_size; (void)ws_size;
  const float* x    = (const float*)d_in[0];
  const int*   mask = (const int*)d_in[1];
  const float* wq   = (const float*)d_in[2];
  const float* bq   = (const float*)d_in[3];
  const float* wk   = (const float*)d_in[4];
  const float* bk   = (const float*)d_in[5];
  const float* wv   = (const float*)d_in[6];
  const float* bv   = (const float*)d_in[7];
  const float* wo   = (const float*)d_in[8];
  const float* bo   = (const float*)d_in[9];
  const float* w1   = (const float*)d_in[10];
  const float* b1   = (const float*)d_in[11];
  const float* w2   = (const float*)d_in[12];
  const float* b2   = (const float*)d_in[13];
  const float* ln1a = (const float*)d_in[14];
  const float* ln1b = (const float*)d_in[15];
  const float* ln2a = (const float*)d_in[16];
  const float* ln2b = (const float*)d_in[17];

  char* ws = (char*)d_ws;
  unsigned short* w_bf  = (unsigned short*)ws;            // 24 MB bf16 weights
  unsigned short* wq_bf = w_bf;
  unsigned short* wo_bf = w_bf + (3u << 20);
  unsigned short* w1_bf = w_bf + (4u << 20);
  unsigned short* w2_bf = w_bf + (8u << 20);
  unsigned short* h1    = (unsigned short*)(ws + (24u << 20));
  unsigned short* qbuf  = (unsigned short*)(ws + (32u << 20));
  unsigned short* kbuf  = (unsigned short*)(ws + (40u << 20));
  unsigned short* vtbuf = (unsigned short*)(ws + (48u << 20));
  unsigned short* attnb = (unsigned short*)(ws + (56u << 20));
  float*          x2    = (float*)(ws + (64u << 20));     // 16 MB
  unsigned short* h2    = (unsigned short*)(ws + (80u << 20));
  unsigned short* ffn1  = (unsigned short*)(ws + (88u << 20));  // 32 MB -> 120
  float*          pp    = (float*)(ws + (88u << 20));     // proj partials (2x16MB,
                                                          // dead before ffn1 use)
  float*          qq    = (float*)(ws + (24u << 20));     // ffn2 partials (2x16MB,
                                                          // h1..attnb dead by then)

  cast_weights_kernel<<<1024, 256, 0, stream>>>(wq, wk, wv, wo, w1, w2, w_bf);
  ln_kernel<<<MROWS, 256, 0, stream>>>(x, ln1a, ln1b, h1);
  gemm_qkv<<<dim3(24, 32), 256, 0, stream>>>(h1, wq_bf, bq, bk, bv, qbuf, vtbuf);
  attn_kernel<<<dim3(32, 32), 256, 0, stream>>>(qbuf, kbuf, vtbuf, mask, attnb);
  gemm_bt<MODE_PARTIAL><<<dim3(8, 32, 2), 256, 0, stream>>>(
      attnb, wo_bf, nullptr, (void*)pp, MROWS, D_MODEL, 512);
  proj_ln2_kernel<<<MROWS, 256, 0, stream>>>(
      x, pp, pp + (size_t)MROWS * D_MODEL, bo, ln2a, ln2b, x2, h2);
  gemm_bt<MODE_RELU><<<dim3(32, 32), 256, 0, stream>>>(
      h2, w1_bf, b1, (void*)ffn1, MROWS, DFF, D_MODEL);
  gemm_bt<MODE_PARTIAL><<<dim3(8, 32, 2), 256, 0, stream>>>(
      ffn1, w2_bf, nullptr, (void*)qq, MROWS, D_MODEL, 2048);
  ffn2_add_kernel<<<4096, 256, 0, stream>>>(
      x2, qq, qq + (size_t)MROWS * D_MODEL, b2, (float*)d_out);
}

// Round 5
// 295.872 us; speedup vs baseline: 1.5168x; 1.0048x over previous
//
#include <hip/hip_runtime.h>
#include <cstdint>
#include <cstddef>

// ---------------------------------------------------------------------------
// Types / helpers
// ---------------------------------------------------------------------------
typedef short bf16x8 __attribute__((ext_vector_type(8)));
typedef short bf16x4 __attribute__((ext_vector_type(4)));
typedef float f32x4 __attribute__((ext_vector_type(4)));

#define D_MODEL 1024
#define SEQ     2048
#define NBATCH  2
#define NH      16
#define DKH     64
#define DFF     4096
#define MROWS   (NBATCH * SEQ)   // 4096

// PV via 16x16x16 MFMA (P-fragment is in-lane, no shuffles)
#if __has_builtin(__builtin_amdgcn_mfma_f32_16x16x16bf16_1k)
#define HAVE_MFMA16 1
#define MFMA16(a, b, c) __builtin_amdgcn_mfma_f32_16x16x16bf16_1k(a, b, c, 0, 0, 0)
#elif __has_builtin(__builtin_amdgcn_mfma_f32_16x16x16_bf16)
#define HAVE_MFMA16 1
#define MFMA16(a, b, c) __builtin_amdgcn_mfma_f32_16x16x16_bf16(a, b, c, 0, 0, 0)
#else
#define HAVE_MFMA16 0
#endif

__device__ __forceinline__ unsigned short f2bf(float f) {
  unsigned u = __builtin_bit_cast(unsigned, f);
  u += 0x7fffu + ((u >> 16) & 1u);          // round-to-nearest-even
  return (unsigned short)(u >> 16);
}
__device__ __forceinline__ unsigned packbf2(float lo, float hi) {
  unsigned r;
  asm("v_cvt_pk_bf16_f32 %0, %1, %2" : "=v"(r) : "v"(lo), "v"(hi));
  return r;
}
__device__ __forceinline__ void gload_lds16(const void* g, void* l) {
  __builtin_amdgcn_global_load_lds(
      (const __attribute__((address_space(1))) unsigned*)g,
      (__attribute__((address_space(3))) unsigned*)l, 16, 0, 0);
}

// ---------------------------------------------------------------------------
// Weight cast f32 -> bf16 + mask -> float addend (0 / -1e9).
// dst layout: [wq 1M][wk 1M][wv 1M][wo 1M][w1 4M][w2 4M]
// ---------------------------------------------------------------------------
__global__ __launch_bounds__(256) void cast_weights_kernel(
    const float* __restrict__ wq, const float* __restrict__ wk,
    const float* __restrict__ wv, const float* __restrict__ wo,
    const float* __restrict__ w1, const float* __restrict__ w2,
    const int* __restrict__ mask, unsigned short* __restrict__ dst,
    float* __restrict__ maskf) {
  const int TOT4 = (12 << 20) >> 2;
  const int gid = blockIdx.x * blockDim.x + threadIdx.x;
  for (int i4 = gid; i4 < TOT4; i4 += gridDim.x * blockDim.x) {
    int i = i4 << 2;
    const float* src;
    int off;
    if (i < (4 << 20)) {
      src = (i < (2 << 20)) ? ((i < (1 << 20)) ? wq : wk)
                            : ((i < (3 << 20)) ? wv : wo);
      off = i & ((1 << 20) - 1);
    } else if (i < (8 << 20)) { src = w1; off = i - (4 << 20); }
    else                      { src = w2; off = i - (8 << 20); }
    float4 v = *(const float4*)(src + off);
    ushort4 o;
    o.x = f2bf(v.x); o.y = f2bf(v.y); o.z = f2bf(v.z); o.w = f2bf(v.w);
    *(ushort4*)(dst + i) = o;
  }
  if (gid < (NBATCH * SEQ / 4)) {
    int4 m = ((const int4*)mask)[gid];
    float4 f;
    f.x = (m.x == 0) ? -1e9f : 0.f;
    f.y = (m.y == 0) ? -1e9f : 0.f;
    f.z = (m.z == 0) ? -1e9f : 0.f;
    f.w = (m.w == 0) ? -1e9f : 0.f;
    ((float4*)maskf)[gid] = f;
  }
}

// ---------------------------------------------------------------------------
// LayerNorm (torch semantics: unbiased std, eps added to std) -> bf16
// ---------------------------------------------------------------------------
__global__ __launch_bounds__(256) void ln_kernel(
    const float* __restrict__ x, const float* __restrict__ alpha,
    const float* __restrict__ beta, unsigned short* __restrict__ out) {
  const int row = blockIdx.x;
  const int t = threadIdx.x;
  float4 v = *(const float4*)(x + (size_t)row * D_MODEL + t * 4);
  float s = v.x + v.y + v.z + v.w;
#pragma unroll
  for (int o = 1; o < 64; o <<= 1) s += __shfl_xor(s, o, 64);
  __shared__ float red[8];
  if ((t & 63) == 0) red[t >> 6] = s;
  __syncthreads();
  float mean = (red[0] + red[1] + red[2] + red[3]) * (1.f / D_MODEL);
  float dx = v.x - mean, dy = v.y - mean, dz = v.z - mean, dw = v.w - mean;
  float sq = dx * dx + dy * dy + dz * dz + dw * dw;
#pragma unroll
  for (int o = 1; o < 64; o <<= 1) sq += __shfl_xor(sq, o, 64);
  if ((t & 63) == 0) red[4 + (t >> 6)] = sq;
  __syncthreads();
  float var = (red[4] + red[5] + red[6] + red[7]) * (1.f / (D_MODEL - 1));
  float inv = 1.f / (sqrtf(var) + 1e-6f);
  float4 a = *(const float4*)(alpha + t * 4);
  float4 be = *(const float4*)(beta + t * 4);
  ushort4 o4;
  o4.x = f2bf(a.x * dx * inv + be.x);
  o4.y = f2bf(a.y * dy * inv + be.y);
  o4.z = f2bf(a.z * dz * inv + be.z);
  o4.w = f2bf(a.w * dw * inv + be.w);
  *(ushort4*)(out + (size_t)row * D_MODEL + t * 4) = o4;
}

// ---------------------------------------------------------------------------
// GEMM core macros (128x128 tile, BK=32, 4 waves 2x2, double-buffered LDS)
// C[m][n] = sum_k A[m][k] * W[n][k]   (torch Linear: x @ W^T)
// ---------------------------------------------------------------------------
#define GEMM_STAGE(A_, W_, LD_, koff_, kt_, buf_)                                  \
  {                                                                                \
    int ke_ = (koff_) + (kt_) * 32;                                                \
    gload_lds16(A_ + (size_t)(m0 + srow) * (LD_) + ke_ + sce, &lds[(buf_)][0][t * 8]);        \
    gload_lds16(A_ + (size_t)(m0 + 64 + srow) * (LD_) + ke_ + sce, &lds[(buf_)][0][2048 + t * 8]); \
    gload_lds16(W_ + (size_t)(n0 + srow) * (LD_) + ke_ + sce, &lds[(buf_)][1][t * 8]);        \
    gload_lds16(W_ + (size_t)(n0 + 64 + srow) * (LD_) + ke_ + sce, &lds[(buf_)][1][2048 + t * 8]); \
  }

#define GEMM_MAINLOOP(A_, W_, LD_, K_, koff_)                                      \
  GEMM_STAGE(A_, W_, LD_, koff_, 0, 0);                                            \
  for (int kt = 0; kt < ((K_) >> 5); ++kt) {                                       \
    __syncthreads();                                                               \
    if (kt + 1 < ((K_) >> 5)) GEMM_STAGE(A_, W_, LD_, koff_, kt + 1, (kt + 1) & 1); \
    const unsigned short* la = lds[kt & 1][0];                                     \
    const unsigned short* lb = lds[kt & 1][1];                                     \
    bf16x8 af[4], bfr[4];                                                          \
    _Pragma("unroll") for (int i = 0; i < 4; i++) {                                \
      af[i]  = *(const bf16x8*)&la[(wm + i * 16 + c) * 32 + g * 8];                \
      bfr[i] = *(const bf16x8*)&lb[(wn + i * 16 + c) * 32 + g * 8];                \
    }                                                                              \
    _Pragma("unroll") for (int mi = 0; mi < 4; mi++)                               \
      _Pragma("unroll") for (int ni = 0; ni < 4; ni++)                             \
        acc[mi][ni] = __builtin_amdgcn_mfma_f32_16x16x32_bf16(af[mi], bfr[ni],     \
                                                              acc[mi][ni], 0, 0, 0); \
  }

enum { MODE_BF16 = 0, MODE_RELU = 2, MODE_PARTIAL = 4 };

template <int MODE>
__global__ __launch_bounds__(256) void gemm_bt(
    const unsigned short* __restrict__ A, const unsigned short* __restrict__ W,
    const float* __restrict__ bias, void* __restrict__ outp, int M, int N, int K) {
  __shared__ unsigned short lds[2][2][128 * 32];
  const int t = threadIdx.x;
  const int lane = t & 63, wid = t >> 6;
  const int g = lane >> 4, c = lane & 15;
  const int m0 = blockIdx.y * 128, n0 = blockIdx.x * 128;
  const int wm = (wid >> 1) * 64, wn = (wid & 1) * 64;
  const int srow = t >> 2, sce = (t & 3) * 8;
  const int ldk = K * gridDim.z;
  const int koff = blockIdx.z * K;

  f32x4 zero = {0.f, 0.f, 0.f, 0.f};
  f32x4 acc[4][4];
#pragma unroll
  for (int i = 0; i < 4; i++)
#pragma unroll
    for (int j = 0; j < 4; j++) acc[i][j] = zero;

  GEMM_MAINLOOP(A, W, ldk, K, koff);

  float bv[4];
#pragma unroll
  for (int ni = 0; ni < 4; ni++)
    bv[ni] = (MODE == MODE_PARTIAL) ? 0.f : bias[n0 + wn + ni * 16 + c];

  float* po = (MODE == MODE_PARTIAL)
                  ? ((float*)outp + (size_t)blockIdx.z * M * N) : (float*)outp;

#pragma unroll
  for (int mi = 0; mi < 4; mi++) {
#pragma unroll
    for (int ni = 0; ni < 4; ni++) {
      const int mb = m0 + wm + mi * 16 + g * 4;
      const int n = n0 + wn + ni * 16 + c;
#pragma unroll
      for (int r = 0; r < 4; r++) {
        const int m = mb + r;
        float v = acc[mi][ni][r] + bv[ni];
        if (MODE == MODE_RELU) v = fmaxf(v, 0.f);
        if (MODE == MODE_PARTIAL) {
          po[(size_t)m * N + n] = v;
        } else {
          ((unsigned short*)outp)[(size_t)m * N + n] = f2bf(v);
        }
      }
    }
  }
}

// Fused QKV GEMM: grid.x = 24 (3 weights x 8 n-tiles). Q written pre-scaled by
// 1/sqrt(d_k); Q,K (B*S,1024) bf16; V written transposed as Vt (B,H,dk,S) bf16.
__global__ __launch_bounds__(256) void gemm_qkv(
    const unsigned short* __restrict__ A, const unsigned short* __restrict__ Wbase,
    const float* __restrict__ bq, const float* __restrict__ bk,
    const float* __restrict__ bv_, unsigned short* __restrict__ qkout,
    unsigned short* __restrict__ vtout) {
  __shared__ unsigned short lds[2][2][128 * 32];
  const int t = threadIdx.x;
  const int lane = t & 63, wid = t >> 6;
  const int g = lane >> 4, c = lane & 15;
  const int wsel = blockIdx.x >> 3;
  const int m0 = blockIdx.y * 128, n0 = (blockIdx.x & 7) * 128;
  const int wm = (wid >> 1) * 64, wn = (wid & 1) * 64;
  const int srow = t >> 2, sce = (t & 3) * 8;
  const unsigned short* W = Wbase + ((size_t)wsel << 20);
  const float* bias = (wsel == 0) ? bq : (wsel == 1) ? bk : bv_;

  f32x4 zero = {0.f, 0.f, 0.f, 0.f};
  f32x4 acc[4][4];
#pragma unroll
  for (int i = 0; i < 4; i++)
#pragma unroll
    for (int j = 0; j < 4; j++) acc[i][j] = zero;

  GEMM_MAINLOOP(A, W, 1024, 1024, 0);

  float bvv[4];
#pragma unroll
  for (int ni = 0; ni < 4; ni++) bvv[ni] = bias[n0 + wn + ni * 16 + c];
  const float qsc = (wsel == 0) ? 0.125f : 1.f;   // fold 1/sqrt(64) into Q

  if (wsel < 2) {
    unsigned short* outp = qkout + ((size_t)wsel << 22);  // q then k
#pragma unroll
    for (int mi = 0; mi < 4; mi++) {
#pragma unroll
      for (int ni = 0; ni < 4; ni++) {
        const int mb = m0 + wm + mi * 16 + g * 4;
        const int n = n0 + wn + ni * 16 + c;
#pragma unroll
        for (int r = 0; r < 4; r++)
          outp[(size_t)(mb + r) * 1024 + n] = f2bf((acc[mi][ni][r] + bvv[ni]) * qsc);
      }
    }
  } else {
    // V^T: out[(b*1024 + n)*2048 + s], n = h*64+dk, m = b*2048+s
#pragma unroll
    for (int mi = 0; mi < 4; mi++) {
#pragma unroll
      for (int ni = 0; ni < 4; ni++) {
        const int mb = m0 + wm + mi * 16 + g * 4;
        const int n = n0 + wn + ni * 16 + c;
        const int b = mb >> 11, s2 = mb & 2047;
        ushort4 o4;
        o4.x = f2bf(acc[mi][ni][0] + bvv[ni]);
        o4.y = f2bf(acc[mi][ni][1] + bvv[ni]);
        o4.z = f2bf(acc[mi][ni][2] + bvv[ni]);
        o4.w = f2bf(acc[mi][ni][3] + bvv[ni]);
        *(ushort4*)(vtout + ((size_t)(b * 1024 + n)) * 2048 + s2) = o4;
      }
    }
  }
}

// ---------------------------------------------------------------------------
// Flash attention. grid = (S/32, B*H), 128 thr = 2 waves x 16 q-rows
// (2048 blocks = 8/CU for occupancy). K,V^T staged via global_load_lds with
// XOR chunk-swizzle on the GLOBAL source; double-buffered; 1 barrier/tile.
// S^T = mfma_16x16x32(K, Q); defer-max online softmax;
// PV = 2x mfma_16x16x16(V^T, P^T) -- P-fragment is in-lane (no shuffles).
// ---------------------------------------------------------------------------
#define ATTN_STAGE(base_, buf_)                                                     \
  {                                                                                 \
    const int i0 = t, i1 = t + 128;                                                 \
    gload_lds16(Kb + (size_t)((base_) + (i0 >> 3)) * D_MODEL +                      \
                    (((i0 & 7) ^ ((i0 >> 3) & 7)) << 3), &Klds[buf_][i0 * 8]);      \
    gload_lds16(Kb + (size_t)((base_) + (i1 >> 3)) * D_MODEL +                      \
                    (((i1 & 7) ^ ((i1 >> 3) & 7)) << 3), &Klds[buf_][i1 * 8]);      \
    gload_lds16(Vb + (size_t)(i0 >> 2) * SEQ + (base_) +                            \
                    (((i0 & 3) ^ ((i0 >> 2) & 3)) << 3), &Vlds[buf_][i0 * 8]);      \
    gload_lds16(Vb + (size_t)(i1 >> 2) * SEQ + (base_) +                            \
                    (((i1 & 3) ^ ((i1 >> 2) & 3)) << 3), &Vlds[buf_][i1 * 8]);      \
  }

__global__ __launch_bounds__(128, 4) void attn_kernel(
    const unsigned short* __restrict__ Q, const unsigned short* __restrict__ Kmat,
    const unsigned short* __restrict__ Vt, const float* __restrict__ maskf,
    unsigned short* __restrict__ O) {
  __shared__ unsigned short Klds[2][32 * 64];
  __shared__ unsigned short Vlds[2][64 * 32];
  const int t = threadIdx.x, lane = t & 63, wid = t >> 6;
  const int g = lane >> 4, c = lane & 15;
  const int qt = blockIdx.x, bh = blockIdx.y;
  const int b = bh >> 4, h = bh & 15;
  const int q0 = qt * 32 + wid * 16;

  const unsigned short* Qb = Q + (size_t)b * SEQ * D_MODEL + h * DKH;
  const unsigned short* Kb = Kmat + (size_t)b * SEQ * D_MODEL + h * DKH;
  const unsigned short* Vb = Vt + (size_t)bh * DKH * SEQ;
  const float* mbf = maskf + b * SEQ;

  bf16x8 qf[2];
#pragma unroll
  for (int kd = 0; kd < 2; kd++)
    qf[kd] = *(const bf16x8*)&Qb[(size_t)(q0 + c) * D_MODEL + kd * 32 + g * 8];

  f32x4 zero = {0.f, 0.f, 0.f, 0.f};
  f32x4 of[4];
#pragma unroll
  for (int j = 0; j < 4; j++) of[j] = zero;
  float mrun = -1e30f, lrun = 0.f;

  ATTN_STAGE(0, 0);

  for (int kv = 0; kv < 64; ++kv) {
    const int buf = kv & 1;
    const int base = kv * 32;
    __syncthreads();                       // drains gloads of this buf
    if (kv < 63) ATTN_STAGE(base + 32, buf ^ 1);

    // K fragments: row nb*16+c, global chunk kd*4+g -> LDS chunk ^ (c&7)
    bf16x8 kf[4];
#pragma unroll
    for (int nb = 0; nb < 2; nb++)
#pragma unroll
      for (int kd = 0; kd < 2; kd++)
        kf[nb * 2 + kd] = *(const bf16x8*)&Klds[buf][(nb * 16 + c) * 64 +
                                                     (((kd * 4 + g) ^ (c & 7)) << 3)];
#if HAVE_MFMA16
    // V fragments for K=16 PV: A[row=dk(c)][k=kv(g*4+j)], 8B each, issued early
    bf16x4 vv[2][4];
#pragma unroll
    for (int nb = 0; nb < 2; nb++)
#pragma unroll
      for (int dkb = 0; dkb < 4; dkb++) {
        const int vrow = dkb * 16 + c;
        const int vbyte = vrow * 64 + ((((nb << 1) + (g >> 1)) ^ (c & 3)) << 4) +
                          ((g & 1) << 3);
        vv[nb][dkb] = *(const bf16x4*)((const char*)Vlds[buf] + vbyte);
      }
#else
    bf16x8 vf[4];
#pragma unroll
    for (int dkb = 0; dkb < 4; dkb++)
      vf[dkb] = *(const bf16x8*)&Vlds[buf][(dkb * 16 + c) * 32 +
                                           ((g ^ (c & 3)) << 3)];
#endif

    float4 ma0 = *(const float4*)&mbf[base + g * 4];
    float4 ma1 = *(const float4*)&mbf[base + 16 + g * 4];

    // S^T[kv][q] (Q pre-scaled by 1/8)
    f32x4 sf[2];
#pragma unroll
    for (int nb = 0; nb < 2; nb++) {
      f32x4 s = zero;
      s = __builtin_amdgcn_mfma_f32_16x16x32_bf16(kf[nb * 2 + 0], qf[0], s, 0, 0, 0);
      s = __builtin_amdgcn_mfma_f32_16x16x32_bf16(kf[nb * 2 + 1], qf[1], s, 0, 0, 0);
      sf[nb] = s;
    }

    // additive mask (pre-converted to 0/-1e9 floats)
    sf[0][0] += ma0.x; sf[0][1] += ma0.y; sf[0][2] += ma0.z; sf[0][3] += ma0.w;
    sf[1][0] += ma1.x; sf[1][1] += ma1.y; sf[1][2] += ma1.z; sf[1][3] += ma1.w;

    // online softmax with defer-max (THR=8)
    float pm = fmaxf(fmaxf(fmaxf(sf[0][0], sf[0][1]), fmaxf(sf[0][2], sf[0][3])),
                     fmaxf(fmaxf(sf[1][0], sf[1][1]), fmaxf(sf[1][2], sf[1][3])));
    pm = fmaxf(pm, __shfl_xor(pm, 16, 64));
    pm = fmaxf(pm, __shfl_xor(pm, 32, 64));
    if (!__all(pm <= mrun + 8.f)) {
      float mnew = fmaxf(mrun, pm);
      float fsc = exp2f((mrun - mnew) * 1.44269504f);
      lrun *= fsc;
#pragma unroll
      for (int dkb = 0; dkb < 4; dkb++) of[dkb] *= fsc;
      mrun = mnew;
    }
    const float mb2 = mrun * 1.44269504f;
    float ps = 0.f;
#pragma unroll
    for (int nb = 0; nb < 2; nb++)
#pragma unroll
      for (int r = 0; r < 4; r++) {
        float p = exp2f(fmaf(sf[nb][r], 1.44269504f, -mb2));
        sf[nb][r] = p;
        ps += p;
      }
    lrun += ps;

#if HAVE_MFMA16
    // PV: of[dkb] += V^T-frag x P^T-frag, K=16 per nb block; P is in-lane:
    // B[k=g*4+j][col=c] = S^T[kv=nb*16+g*4+j][q=c] = sf[nb][j] of this lane.
#pragma unroll
    for (int nb = 0; nb < 2; nb++) {
      unsigned plo = packbf2(sf[nb][0], sf[nb][1]);
      unsigned phi = packbf2(sf[nb][2], sf[nb][3]);
      unsigned long long uu = (unsigned long long)plo |
                              ((unsigned long long)phi << 32);
      bf16x4 pf = __builtin_bit_cast(bf16x4, uu);
#pragma unroll
      for (int dkb = 0; dkb < 4; dkb++)
        of[dkb] = MFMA16(vv[nb][dkb], pf, of[dkb]);
    }
#else
    // fallback: redistribute P^T via shfl into K=32 B-fragment
    unsigned pk00 = packbf2(sf[0][0], sf[0][1]);
    unsigned pk01 = packbf2(sf[0][2], sf[0][3]);
    unsigned pk10 = packbf2(sf[1][0], sf[1][1]);
    unsigned pk11 = packbf2(sf[1][2], sf[1][3]);
    const int la = ((g & 1) << 5) + c;
    const int lb2 = la + 16;
    unsigned a00 = __shfl(pk00, la, 64), a01 = __shfl(pk01, la, 64);
    unsigned a10 = __shfl(pk10, la, 64), a11 = __shfl(pk11, la, 64);
    unsigned b00 = __shfl(pk00, lb2, 64), b01 = __shfl(pk01, lb2, 64);
    unsigned b10 = __shfl(pk10, lb2, 64), b11 = __shfl(pk11, lb2, 64);
    const bool hi2 = (g >= 2);
    uint4 pw;
    pw.x = hi2 ? a10 : a00;
    pw.y = hi2 ? a11 : a01;
    pw.z = hi2 ? b10 : b00;
    pw.w = hi2 ? b11 : b01;
    bf16x8 pf = __builtin_bit_cast(bf16x8, pw);
#pragma unroll
    for (int dkb = 0; dkb < 4; dkb++)
      of[dkb] = __builtin_amdgcn_mfma_f32_16x16x32_bf16(vf[dkb], pf, of[dkb], 0, 0, 0);
#endif
  }

  float lt = lrun;
  lt += __shfl_xor(lt, 16, 64);
  lt += __shfl_xor(lt, 32, 64);
  float inv = 1.f / lt;
#pragma unroll
  for (int dkb = 0; dkb < 4; dkb++) {
    ushort4 o4;
    o4.x = f2bf(of[dkb][0] * inv);
    o4.y = f2bf(of[dkb][1] * inv);
    o4.z = f2bf(of[dkb][2] * inv);
    o4.w = f2bf(of[dkb][3] * inv);
    *(ushort4*)&O[(size_t)(b * SEQ + q0 + c) * D_MODEL + h * DKH + dkb * 16 +
                  g * 4] = o4;
  }
}

// ---------------------------------------------------------------------------
// Fused epilogues
// proj_ln2: x2 = x + P0 + P1 + bo;  h2 = LN2(x2).  one block per row.
// ---------------------------------------------------------------------------
__global__ __launch_bounds__(256) void proj_ln2_kernel(
    const float* __restrict__ x, const float* __restrict__ P0,
    const float* __restrict__ P1, const float* __restrict__ bo,
    const float* __restrict__ alpha, const float* __restrict__ beta,
    float* __restrict__ x2, unsigned short* __restrict__ h2) {
  const int row = blockIdx.x;
  const int t = threadIdx.x;
  const size_t idx = (size_t)row * D_MODEL + t * 4;
  float4 xv = *(const float4*)(x + idx);
  float4 p0 = *(const float4*)(P0 + idx);
  float4 p1 = *(const float4*)(P1 + idx);
  float4 bo4 = *(const float4*)(bo + t * 4);
  float4 v;
  v.x = xv.x + p0.x + p1.x + bo4.x;
  v.y = xv.y + p0.y + p1.y + bo4.y;
  v.z = xv.z + p0.z + p1.z + bo4.z;
  v.w = xv.w + p0.w + p1.w + bo4.w;
  *(float4*)(x2 + idx) = v;

  float s = v.x + v.y + v.z + v.w;
#pragma unroll
  for (int o = 1; o < 64; o <<= 1) s += __shfl_xor(s, o, 64);
  __shared__ float red[8];
  if ((t & 63) == 0) red[t >> 6] = s;
  __syncthreads();
  float mean = (red[0] + red[1] + red[2] + red[3]) * (1.f / D_MODEL);
  float dx = v.x - mean, dy = v.y - mean, dz = v.z - mean, dw = v.w - mean;
  float sq = dx * dx + dy * dy + dz * dz + dw * dw;
#pragma unroll
  for (int o = 1; o < 64; o <<= 1) sq += __shfl_xor(sq, o, 64);
  if ((t & 63) == 0) red[4 + (t >> 6)] = sq;
  __syncthreads();
  float var = (red[4] + red[5] + red[6] + red[7]) * (1.f / (D_MODEL - 1));
  float inv = 1.f / (sqrtf(var) + 1e-6f);
  float4 a = *(const float4*)(alpha + t * 4);
  float4 be = *(const float4*)(beta + t * 4);
  ushort4 o4;
  o4.x = f2bf(a.x * dx * inv + be.x);
  o4.y = f2bf(a.y * dy * inv + be.y);
  o4.z = f2bf(a.z * dz * inv + be.z);
  o4.w = f2bf(a.w * dw * inv + be.w);
  *(ushort4*)(h2 + idx) = o4;
}

// ffn2_add: out = x2 + Q0 + Q1 + b2  (final output, f32)
__global__ __launch_bounds__(256) void ffn2_add_kernel(
    const float* __restrict__ x2, const float* __restrict__ Q0,
    const float* __restrict__ Q1, const float* __restrict__ b2,
    float* __restrict__ out) {
  const int i4 = blockIdx.x * blockDim.x + threadIdx.x;  // 1M float4s
  const size_t idx = (size_t)i4 * 4;
  float4 a = *(const float4*)(x2 + idx);
  float4 q0 = *(const float4*)(Q0 + idx);
  float4 q1 = *(const float4*)(Q1 + idx);
  float4 b = *(const float4*)(b2 + ((i4 & 255) * 4));
  float4 v;
  v.x = a.x + q0.x + q1.x + b.x;
  v.y = a.y + q0.y + q1.y + b.y;
  v.z = a.z + q0.z + q1.z + b.z;
  v.w = a.w + q0.w + q1.w + b.w;
  *(float4*)(out + idx) = v;
}

// ---------------------------------------------------------------------------
// Launch
// ---------------------------------------------------------------------------
extern "C" void kernel_launch(void* const* d_in, const int* in_sizes, int n_in,
                              void* d_out, int out_size, void* d_ws, size_t ws_size,
                              hipStream_t stream) {
  (void)in_sizes; (void)n_in; (void)out_size; (void)ws_size;
  const float* x    = (const float*)d_in[0];
  const int*   mask = (const int*)d_in[1];
  const float* wq   = (const float*)d_in[2];
  const float* bq   = (const float*)d_in[3];
  const float* wk   = (const float*)d_in[4];
  const float* bk   = (const float*)d_in[5];
  const float* wv   = (const float*)d_in[6];
  const float* bv   = (const float*)d_in[7];
  const float* wo   = (const float*)d_in[8];
  const float* bo   = (const float*)d_in[9];
  const float* w1   = (const float*)d_in[10];
  const float* b1   = (const float*)d_in[11];
  const float* w2   = (const float*)d_in[12];
  const float* b2   = (const float*)d_in[13];
  const float* ln1a = (const float*)d_in[14];
  const float* ln1b = (const float*)d_in[15];
  const float* ln2a = (const float*)d_in[16];
  const float* ln2b = (const float*)d_in[17];

  char* ws = (char*)d_ws;
  unsigned short* w_bf  = (unsigned short*)ws;            // 24 MB bf16 weights
  unsigned short* wq_bf = w_bf;
  unsigned short* wo_bf = w_bf + (3u << 20);
  unsigned short* w1_bf = w_bf + (4u << 20);
  unsigned short* w2_bf = w_bf + (8u << 20);
  unsigned short* h1    = (unsigned short*)(ws + (24u << 20));
  unsigned short* qbuf  = (unsigned short*)(ws + (32u << 20));
  unsigned short* kbuf  = (unsigned short*)(ws + (40u << 20));
  unsigned short* vtbuf = (unsigned short*)(ws + (48u << 20));
  unsigned short* attnb = (unsigned short*)(ws + (56u << 20));
  float*          x2    = (float*)(ws + (64u << 20));     // 16 MB
  unsigned short* h2    = (unsigned short*)(ws + (80u << 20));
  unsigned short* ffn1  = (unsigned short*)(ws + (88u << 20));  // 32 MB -> 120
  float*          pp    = (float*)(ws + (88u << 20));     // proj partials (2x16MB,
                                                          // dead before ffn1 use)
  float*          qq    = (float*)(ws + (24u << 20));     // ffn2 partials (2x16MB,
                                                          // h1..attnb dead by then)
  float*          maskf = (float*)(ws + (120u << 20));    // 16 KB

  cast_weights_kernel<<<1024, 256, 0, stream>>>(wq, wk, wv, wo, w1, w2, mask,
                                                w_bf, maskf);
  ln_kernel<<<MROWS, 256, 0, stream>>>(x, ln1a, ln1b, h1);
  gemm_qkv<<<dim3(24, 32), 256, 0, stream>>>(h1, wq_bf, bq, bk, bv, qbuf, vtbuf);
  attn_kernel<<<dim3(64, 32), 128, 0, stream>>>(qbuf, kbuf, vtbuf, maskf, attnb);
  gemm_bt<MODE_PARTIAL><<<dim3(8, 32, 2), 256, 0, stream>>>(
      attnb, wo_bf, nullptr, (void*)pp, MROWS, D_MODEL, 512);
  proj_ln2_kernel<<<MROWS, 256, 0, stream>>>(
      x, pp, pp + (size_t)MROWS * D_MODEL, bo, ln2a, ln2b, x2, h2);
  gemm_bt<MODE_RELU><<<dim3(32, 32), 256, 0, stream>>>(
      h2, w1_bf, b1, (void*)ffn1, MROWS, DFF, D_MODEL);
  gemm_bt<MODE_PARTIAL><<<dim3(8, 32, 2), 256, 0, stream>>>(
      ffn1, w2_bf, nullptr, (void*)qq, MROWS, D_MODEL, 2048);
  ffn2_add_kernel<<<4096, 256, 0, stream>>>(
      x2, qq, qq + (size_t)MROWS * D_MODEL, b2, (float*)d_out);
}